// Round 9
// baseline (59.238 us; speedup 1.0000x reference)
//
#include <hip/hip_runtime.h>

#define B_ 2
#define C_ 121
#define H_ 128
#define W_ 256
#define D_ 48
#define CT 7         // channels per chunk; 121 = 17*7 + 2 (tail)
#define NFULL 17
#define NT 256       // 4 waves: 64 w-quads x 4 d-groups
#define NDY 4        // disparities per thread
#define ZS 3         // d-split: 16 d per block
#define XROW 264     // 256 + 8 pad -> bank start rotates by 8 per row
#define YROW 312     // 48 zero-pad + 256 + 8 pad -> rotates by 24
#define NBUF 3

constexpr int HW = H_ * W_;

typedef float f32x4 __attribute__((ext_vector_type(4)));
typedef const void __attribute__((address_space(1)))* gas1_t;
typedef void __attribute__((address_space(3)))* las3_t;

#define VMWAIT(NSTR) asm volatile("s_waitcnt vmcnt(" NSTR ")" ::: "memory")
#define CFENCE()     asm volatile("" ::: "memory")

// chunks whose channel range contains a prefix boundary (c+1 = kk^2):
// c=8->k1, 15->k2, 24->k3, 35->k5, 48->k6, 63->k9, 80->k11, 99->k14 (120 in tail)
constexpr unsigned SBm = (1u<<1)|(1u<<2)|(1u<<3)|(1u<<5)|(1u<<6)|(1u<<9)|(1u<<11)|(1u<<14);

__device__ __forceinline__ void vmwait_n(int n) {
    switch (n) {                    // wave-uniform scalar branch
        case 3:  VMWAIT("3");  break;
        case 4:  VMWAIT("4");  break;
        case 7:  VMWAIT("7");  break;
        case 8:  VMWAIT("8");  break;
        case 11: VMWAIT("11"); break;
        default: VMWAIT("12"); break;
    }
}

__launch_bounds__(NT, 3)
__global__ void cost_volume_kernel(const float* __restrict__ xg,
                                   const float* __restrict__ yg,
                                   float* __restrict__ out)
{
    __shared__ __align__(16) float XLS[NBUF][CT][XROW];
    __shared__ __align__(16) float YLS[NBUF][CT][YROW];

    const int t  = threadIdx.x;
    const int h  = blockIdx.x;
    const int b  = blockIdx.y;
    const int z  = blockIdx.z;          // owns d in [z*16, z*16+16)
    const int wq = t & 63;
    const int wv = t >> 6;              // wave id = d-group
    const int d0 = z * 16 + wv * NDY;   // multiple of 4
    const int w0 = wq * 4;
    const int bp = w0 - d0 + 44;        // mult of 4; window idx [1,7]; bp+7 <= 303

    // zero y left pads (p<48). Pad values only feed masked (w<d) outputs —
    // the cndmask selects literal 0 — so no cross-wave sync is needed here.
    for (int i = t; i < NBUF * CT * 48; i += NT) {
        int nb = i / (CT * 48);
        int r  = i % (CT * 48);
        YLS[nb][r / 48][r % 48] = 0.0f;
    }

    const size_t row0 = (((size_t)b * C_) * H_ + h) * (size_t)W_;
    const float* xrow = xg + row0 + (size_t)wq * 4;
    const float* yrow = yg + row0 + (size_t)wq * 4;

    // cooperative stage: 14 rows/chunk; per-wave DMA count: wv0,1 -> 4; wv2,3 -> 3
    auto stage = [&](int chunk, int nb) {
        for (int i = wv; i < 2 * CT; i += 4) {
            const int cc = i >> 1;
            const size_t off = (size_t)(chunk * CT + cc) * HW;
            if (i & 1)
                __builtin_amdgcn_global_load_lds((gas1_t)(yrow + off),
                                                 (las3_t)&YLS[nb][cc][48], 16, 0, 0);
            else
                __builtin_amdgcn_global_load_lds((gas1_t)(xrow + off),
                                                 (las3_t)&XLS[nb][cc][0], 16, 0, 0);
        }
    };
    // tail: c=119,120 -> buf 2, rows cc=0,1; exactly 1 DMA per wave
    auto stage_tail = [&]() {
        const int cc = wv >> 1;
        const size_t off = (size_t)(119 + cc) * HW;
        if (wv & 1)
            __builtin_amdgcn_global_load_lds((gas1_t)(yrow + off),
                                             (las3_t)&YLS[2][cc][48], 16, 0, 0);
        else
            __builtin_amdgcn_global_load_lds((gas1_t)(xrow + off),
                                             (las3_t)&XLS[2][cc][0], 16, 0, 0);
    };

    float acc[NDY][4] = {};

    auto chan = [&](int nb, int cc, int ch) {
        const f32x4 xv = *(const f32x4*)&XLS[nb][cc][w0];
        float yw[8];
        *(f32x4*)&yw[0] = *(const f32x4*)&YLS[nb][cc][bp];
        *(f32x4*)&yw[4] = *(const f32x4*)&YLS[nb][cc][bp + 4];
        const float xvv[4] = {xv.x, xv.y, xv.z, xv.w};
        #pragma unroll
        for (int jd = 0; jd < NDY; ++jd)
            #pragma unroll
            for (int jw = 0; jw < 4; ++jw)
                acc[jd][jw] += __builtin_fabsf(xvv[jw] - yw[4 + jw - jd]);

        constexpr int KB[9] = {8, 15, 24, 35, 48, 63, 80, 99, 120};
        #pragma unroll
        for (int bi = 0; bi < 9; ++bi) {
            if (ch == KB[bi]) {      // wave-uniform scalar compare
                const float inv = 1.0f / (float)(KB[bi] + 1);
                const size_t obase = (((size_t)b * 9 + bi) * D_) * (size_t)HW
                                   + (size_t)h * W_ + (size_t)w0;
                #pragma unroll
                for (int jd = 0; jd < NDY; ++jd) {
                    const int d = d0 + jd;
                    f32x4 v;
                    v.x = (w0 + 0 >= d) ? acc[jd][0] * inv : 0.0f;
                    v.y = (w0 + 1 >= d) ? acc[jd][1] * inv : 0.0f;
                    v.z = (w0 + 2 >= d) ? acc[jd][2] * inv : 0.0f;
                    v.w = (w0 + 3 >= d) ? acc[jd][3] * inv : 0.0f;
                    *(f32x4*)&out[obase + (size_t)d * HW] = v;
                }
            }
        }
    };

    stage(0, 0);
    stage(1, 1);

    for (int k = 0; k < NFULL; ++k) {
        const int nb = k % 3;
        // exact allowable outstanding = cnt(stage(k+1)) + stores(k-1) + stores(k-2)
        // (everything issued after stage(k)); guarantees stage(k) retired without
        // ever waiting on in-flight stores or the next prefetch.
        const int nw = (wv < 2 ? 4 : 3)
                     + ((k >= 1 && ((SBm >> (k - 1)) & 1)) ? 4 : 0)
                     + ((k >= 2 && ((SBm >> (k - 2)) & 1)) ? 4 : 0);
        vmwait_n(nw);
        __builtin_amdgcn_s_barrier();   // all waves done reading chunk k-1
        CFENCE();
        if (k + 2 < NFULL)       stage(k + 2, (k + 2) % 3);  // overwrites buf(k-1)
        else if (k + 2 == NFULL) stage_tail();
        CFENCE();
        #pragma unroll
        for (int cc = 0; cc < CT; ++cc)
            chan(nb, cc, k * CT + cc);
    }

    // tail chunk: c=119,120 in buf 2 (chunks 15,16 issued no stores -> wait(0) cheap)
    VMWAIT("0");
    __builtin_amdgcn_s_barrier();
    CFENCE();
    chan(2, 0, 119);
    chan(2, 1, 120);
}

extern "C" void kernel_launch(void* const* d_in, const int* in_sizes, int n_in,
                              void* d_out, int out_size, void* d_ws, size_t ws_size,
                              hipStream_t stream)
{
    const float* x = (const float*)d_in[0];
    const float* y = (const float*)d_in[1];
    float* o = (float*)d_out;
    dim3 grid(H_, B_, ZS);   // z slowest: d-split siblings 256 ids apart -> same XCD
    dim3 block(NT, 1, 1);
    hipLaunchKernelGGL(cost_volume_kernel, grid, block, 0, stream, x, y, o);
}